// Round 12
// baseline (189.078 us; speedup 1.0000x reference)
//
#include <hip/hip_runtime.h>
#include <hip/hip_bf16.h>

#define B_  2
#define S_  4096
#define E_  512
#define H_  8
#define DK_ 64
#define M_  8192  // B_*S_

typedef float f32x4  __attribute__((ext_vector_type(4)));
typedef float f32x16 __attribute__((ext_vector_type(16)));
typedef short s16x8  __attribute__((ext_vector_type(8)));
typedef short s16x4  __attribute__((ext_vector_type(4)));

static __device__ __forceinline__ short f2bf(float x) {
  __hip_bfloat16 h = __float2bfloat16(x);
  return __builtin_bit_cast(short, h);
}

static __device__ __forceinline__ f32x4 mfma32(s16x8 a, s16x8 b, f32x4 c) {
  return __builtin_amdgcn_mfma_f32_16x16x32_bf16(a, b, c, 0, 0, 0);
}

static __device__ __forceinline__ f32x16 mfma3232(s16x8 a, s16x8 b, f32x16 c) {
  return __builtin_amdgcn_mfma_f32_32x32x16_bf16(a, b, c, 0, 0, 0);
}

// 2^x. Compiler intrinsic (proper hazard handling — raw inline-asm v_exp_f32
// was round-3's correctness bug). Fallback: e^(x ln2) via __expf.
static __device__ __forceinline__ float fastexp2(float x) {
#if __has_builtin(__builtin_amdgcn_exp2f)
  return __builtin_amdgcn_exp2f(x);
#else
  return __expf(x * 0.69314718056f);
#endif
}

static __device__ __forceinline__ void gload_lds16(const void* g, void* l) {
  __builtin_amdgcn_global_load_lds(
      (const __attribute__((address_space(1))) unsigned int*)g,
      (__attribute__((address_space(3))) unsigned int*)l, 16, 0, 0);
}

// ---------------- conversion kernels (fused: fewer launches) --------------
__global__ __launch_bounds__(256) void conv_bf16_all(
    const float* __restrict__ q, const float* __restrict__ k,
    const float* __restrict__ v, short* __restrict__ out, int n4) {
  const float* in = (blockIdx.y == 0) ? q : ((blockIdx.y == 1) ? k : v);
  short* o = out + (size_t)blockIdx.y * (size_t)n4 * 4;
  int i = blockIdx.x * 256 + threadIdx.x;
  if (i < n4) {
    float4 x = *((const float4*)in + i);
    s16x4 r;
    r[0] = f2bf(x.x); r[1] = f2bf(x.y); r[2] = f2bf(x.z); r[3] = f2bf(x.w);
    *((s16x4*)o + i) = r;
  }
}

// W [E][E] f32 row-major -> Wt bf16 [N=E][K=E] (transposed); y selects W.
__global__ __launch_bounds__(256) void conv_wT_all(
    const float* __restrict__ Wq, const float* __restrict__ Wk,
    const float* __restrict__ Wv, const float* __restrict__ Wo,
    short* __restrict__ Wt) {
  const float* W = (blockIdx.y == 0) ? Wq
                   : ((blockIdx.y == 1) ? Wk : ((blockIdx.y == 2) ? Wv : Wo));
  short* o = Wt + (size_t)blockIdx.y * (E_ * E_);
  int idx = blockIdx.x * 256 + threadIdx.x;
  int j = idx >> 9, k = idx & 511;
  o[idx] = f2bf(W[(size_t)k * E_ + j]);
}

// ------- GEMM core: 2-phase double-buffered, BK=32, frag-gathered LDS -----
static __device__ __forceinline__ void gemm_core_512(
    const short* __restrict__ A, const short* __restrict__ Bt,
    short* As, short* Bs, int tm, int tn, f32x4 acc[4][4]) {
  const int tid = threadIdx.x;
  const int wave = tid >> 6, lane = tid & 63;
  const int c = lane & 15, g = lane >> 4;
  int fOff[2];
#pragma unroll
  for (int r = 0; r < 2; ++r) {
    const int f = wave * 2 + r;  // frag 0..7
    fOff[r] = ((f >> 2) * 64 + (f & 3) * 16 + c) * 512 + g * 8;
  }
  auto stg = [&](int p, int b) {
#pragma unroll
    for (int r = 0; r < 2; ++r) {
      const int f = wave * 2 + r;
      gload_lds16(A + (size_t)tm * 512 + p * 32 + fOff[r],
                  (char*)As + b * 8192 + f * 1024);
      gload_lds16(Bt + (size_t)tn * 512 + p * 32 + fOff[r],
                  (char*)Bs + b * 8192 + f * 1024);
    }
  };
  stg(0, 0);
  __syncthreads();
  for (int p = 0; p < 16; ++p) {
    if (p + 1 < 16) stg(p + 1, (p + 1) & 1);  // overlaps compute below
    const short* Ac = As + (p & 1) * 4096;
    const short* Bc = Bs + (p & 1) * 4096;
    s16x8 af[4], bfr[4];
#pragma unroll
    for (int i = 0; i < 4; ++i)
      af[i] = *(const s16x8*)(Ac + ((wave >> 1) * 4 + i) * 512 + lane * 8);
#pragma unroll
    for (int j = 0; j < 4; ++j)
      bfr[j] = *(const s16x8*)(Bc + ((wave & 1) * 4 + j) * 512 + lane * 8);
#pragma unroll
    for (int i = 0; i < 4; ++i)
#pragma unroll
      for (int j = 0; j < 4; ++j)
        acc[i][j] = mfma32(af[i], bfr[j], acc[i][j]);
    __syncthreads();  // next buf resident; this buf free for stg(p+2)
  }
}

// QKV projections, batched over blockIdx.z in {0,1,2}.
__global__ __launch_bounds__(256) void gemm_qkv(
    const short* __restrict__ Xq, const short* __restrict__ Xk,
    const short* __restrict__ Xv, const short* __restrict__ Wt,
    const float* __restrict__ bq, const float* __restrict__ bk,
    const float* __restrict__ bv,
    short* __restrict__ Qo, short* __restrict__ Ko, short* __restrict__ Vto) {
  __shared__ __align__(16) short As[2 * 4096];
  __shared__ __align__(16) short Bs[2 * 4096];
  const int z = blockIdx.z;
  const short* A = (z == 0) ? Xq : ((z == 1) ? Xk : Xv);
  const short* Bt = Wt + z * (E_ * E_);
  const float* bias = (z == 0) ? bq : ((z == 1) ? bk : bv);
  const int tm = blockIdx.x * 128, tn = blockIdx.y * 128;
  f32x4 acc[4][4] = {};
  gemm_core_512(A, Bt, As, Bs, tm, tn, acc);

  const int tid = threadIdx.x;
  const int wave = tid >> 6, lane = tid & 63;
  const int wm = (wave >> 1) * 64, wn = (wave & 1) * 64;
  const int c = lane & 15, g = lane >> 4;
#pragma unroll
  for (int i = 0; i < 4; ++i) {
#pragma unroll
    for (int j = 0; j < 4; ++j) {
      const int gc = tn + wn + j * 16 + c;
      const float bb = bias[gc];
      const int h = gc >> 6, dk = gc & 63;
      if (z == 2) {
        const int gr0 = tm + wm + i * 16 + g * 4;
        const int b = gr0 >> 12, s0 = gr0 & 4095;
        s16x4 v4;
#pragma unroll
        for (int r = 0; r < 4; ++r) v4[r] = f2bf(acc[i][j][r] + bb);
        *(s16x4*)&Vto[(size_t)((b * H_ + h) * DK_ + dk) * S_ + s0] = v4;
      } else {
#pragma unroll
        for (int r = 0; r < 4; ++r) {
          const int gr = tm + wm + i * 16 + g * 4 + r;
          const int b = gr >> 12, s = gr & 4095;
          float v = acc[i][j][r] + bb;
          if (z == 0) v *= 1.44269504f;  // Q *= log2(e)
          const short hv = f2bf(v);
          if (z == 1)
            Ko[(size_t)((b * H_ + h) * S_ + s) * DK_ + dk] = hv;
          else
            Qo[(size_t)((b * H_ + h) * S_ + s) * DK_ + dk] = hv;
        }
      }
    }
  }
}

// Output projection: out = AO(bf16) @ Wo + bo, f32 row-major.
__global__ __launch_bounds__(256) void gemm_out(
    const short* __restrict__ AO, const short* __restrict__ Wot,
    const float* __restrict__ bo, float* __restrict__ out) {
  __shared__ __align__(16) short As[2 * 4096];
  __shared__ __align__(16) short Bs[2 * 4096];
  const int tm = blockIdx.x * 128, tn = blockIdx.y * 128;
  f32x4 acc[4][4] = {};
  gemm_core_512(AO, Wot, As, Bs, tm, tn, acc);

  const int tid = threadIdx.x;
  const int wave = tid >> 6, lane = tid & 63;
  const int wm = (wave >> 1) * 64, wn = (wave & 1) * 64;
  const int c = lane & 15, g = lane >> 4;
#pragma unroll
  for (int i = 0; i < 4; ++i) {
#pragma unroll
    for (int j = 0; j < 4; ++j) {
      const int gc = tn + wn + j * 16 + c;
      const float bb = bo[gc];
#pragma unroll
      for (int r = 0; r < 4; ++r) {
        const int gr = tm + wm + i * 16 + g * 4 + r;
        out[(size_t)gr * E_ + gc] = acc[i][j][r] + bb;
      }
    }
  }
}

// ---- flash attention: BARRIER-FREE, K/V fragments direct to registers ----
// Guide common-mistake #7 (m169): K/V per head = 1MB, L2-resident — LDS
// staging was pure overhead AND its per-tile barrier phase-locked all waves
// (the serialization r8/r10 couldn't break). Now each wave loads its 4
// K-frags + 4 V-frags per tile straight global->VGPR (per-lane gather =
// what the LDS read produced; tau-permute folded into the address; each
// frag row is a whole 128B cache line). Register double-buffer with NAMED
// sets (rule #20), load(t+1) issued before compute(t) — compiler inserts
// counted vmcnt waits (G7). ZERO barriers in the main loop: waves drift,
// one wave's exp burst overlaps another's MFMA burst naturally.
// Structure kept from r9: 8 waves = 4 q-groups(64q) x 2 key-halves,
// 2x fragment reuse (each frag feeds 2 MFMAs), no-max softmax (Q pre-scaled
// by log2 e), scalar denominator sums, end-of-kernel key-half merge in LDS.
__global__ __launch_bounds__(512, 2) void attn_fwd(
    const short* __restrict__ Q, const short* __restrict__ K,
    const short* __restrict__ Vt, short* __restrict__ O) {
  __shared__ __align__(16) float mrg[9216];  // merge only (36KB)
  const int tid = threadIdx.x;
  const int wave = tid >> 6, lane = tid & 63;
  const int g = wave >> 1, kh = wave & 1;
  const int qi = lane & 31, hi = lane >> 5;
  const int bh = blockIdx.y;
  const int b = bh >> 3, h = bh & 7;
  const int q0 = blockIdx.x * 256 + g * 64;
  const short* Qp = Q + (size_t)bh * S_ * DK_;
  const short* Kp = K + (size_t)bh * S_ * DK_;
  const short* Vp = Vt + (size_t)bh * DK_ * S_;

  // Q fragments (B-operand), two q-halves
  s16x8 qfL[4], qfH[4];
#pragma unroll
  for (int s = 0; s < 4; ++s) {
    qfL[s] = *(const s16x8*)(Qp + (size_t)(q0 + qi) * DK_ + s * 16 + hi * 8);
    qfH[s] = *(const s16x8*)(Qp + (size_t)(q0 + 32 + qi) * DK_ + s * 16 + hi * 8);
  }

  f32x16 o00 = {}, o01 = {}, o10 = {}, o11 = {};  // o[dkh][qh]
  float lsL = 0.f, lsH = 0.f;                     // denominator partials

  // per-lane gather bases (elements):
  // K frag s: tau(kh*32+qi)*DK + s*16 + hi*8   (+ t*64*DK)
  // V frag (dkh,ks): (dkh*32+qi)*S + kh*32 + ks*16 + hi*8  (+ t*64)
  const int row = kh * 32 + qi;
  const int srow = (row & 32) | ((row & 8) << 1) | ((row & 4) << 1) |
                   ((row & 16) >> 2) | (row & 3);  // tau permute
  const int kBase = srow * DK_ + hi * 8;
  const int vBase0 = qi * S_ + kh * 32 + hi * 8;
  const int vBase1 = (32 + qi) * S_ + kh * 32 + hi * 8;

#define LOADK(t, k0, k1, k2, k3)                                       \
  {                                                                    \
    const short* kp_ = Kp + (size_t)(t) * 64 * DK_ + kBase;            \
    k0 = *(const s16x8*)(kp_);                                         \
    k1 = *(const s16x8*)(kp_ + 16);                                    \
    k2 = *(const s16x8*)(kp_ + 32);                                    \
    k3 = *(const s16x8*)(kp_ + 48);                                    \
  }
#define LOADV(t, v0, v1, v2, v3)                                       \
  {                                                                    \
    const short* vp_ = Vp + (size_t)(t) * 64;                          \
    v0 = *(const s16x8*)(vp_ + vBase0);                                \
    v1 = *(const s16x8*)(vp_ + vBase0 + 16);                           \
    v2 = *(const s16x8*)(vp_ + vBase1);                                \
    v3 = *(const s16x8*)(vp_ + vBase1 + 16);                           \
  }

  // S^T = K(frags in regs) . Q^T : 8 MFMA from 4 frags (2x reuse)
#define QK(k0, k1, k2, k3, sL, sH)                                     \
  {                                                                    \
    f32x16 a_ = {}, c_ = {};                                           \
    __builtin_amdgcn_s_setprio(1);                                     \
    a_ = mfma3232(k0, qfL[0], a_); c_ = mfma3232(k0, qfH[0], c_);      \
    a_ = mfma3232(k1, qfL[1], a_); c_ = mfma3232(k1, qfH[1], c_);      \
    a_ = mfma3232(k2, qfL[2], a_); c_ = mfma3232(k2, qfH[2], c_);      \
    a_ = mfma3232(k3, qfL[3], a_); c_ = mfma3232(k3, qfH[3], c_);      \
    __builtin_amdgcn_s_setprio(0);                                     \
    sL = a_; sH = c_;                                                  \
  }

  // P=2^S; per-lane l sums; pack; PV: 8 MFMA from 4 V frags (2x reuse)
#define SOFTPV(sL, sH, v0, v1, v2, v3)                                 \
  {                                                                    \
    float pL_[16], pH_[16];                                            \
    _Pragma("unroll")                                                  \
    for (int r = 0; r < 16; ++r) {                                     \
      pL_[r] = fastexp2((sL)[r]);                                      \
      pH_[r] = fastexp2((sH)[r]);                                      \
    }                                                                  \
    float aL_ = 0.f, aH_ = 0.f;                                        \
    _Pragma("unroll")                                                  \
    for (int r = 0; r < 16; ++r) { aL_ += pL_[r]; aH_ += pH_[r]; }     \
    lsL += aL_; lsH += aH_;                                            \
    s16x8 pbL_[2], pbH_[2];                                            \
    _Pragma("unroll")                                                  \
    for (int ks = 0; ks < 2; ++ks)                                     \
      _Pragma("unroll")                                                \
      for (int j = 0; j < 8; ++j) {                                    \
        const int r = (j & 3) | (ks << 2) | ((j >> 2) << 3);           \
        pbL_[ks][j] = f2bf(pL_[r]);                                    \
        pbH_[ks][j] = f2bf(pH_[r]);                                    \
      }                                                                \
    __builtin_amdgcn_s_setprio(1);                                     \
    o00 = mfma3232(v0, pbL_[0], o00); o01 = mfma3232(v0, pbH_[0], o01);\
    o10 = mfma3232(v2, pbL_[0], o10); o11 = mfma3232(v2, pbH_[0], o11);\
    o00 = mfma3232(v1, pbL_[1], o00); o01 = mfma3232(v1, pbH_[1], o01);\
    o10 = mfma3232(v3, pbL_[1], o10); o11 = mfma3232(v3, pbH_[1], o11);\
    __builtin_amdgcn_s_setprio(0);                                     \
  }

  s16x8 kA0, kA1, kA2, kA3, vA0, vA1, vA2, vA3;
  s16x8 kB0, kB1, kB2, kB3, vB0, vB1, vB2, vB3;
  f32x16 sL, sH;

  LOADK(0, kA0, kA1, kA2, kA3);
  LOADV(0, vA0, vA1, vA2, vA3);

  const int NT = S_ / 64;
  for (int t = 0; t < NT; t += 2) {
    // prefetch t+1 into B while computing t from A
    LOADK(t + 1, kB0, kB1, kB2, kB3);
    LOADV(t + 1, vB0, vB1, vB2, vB3);
    QK(kA0, kA1, kA2, kA3, sL, sH);
    SOFTPV(sL, sH, vA0, vA1, vA2, vA3);
    // prefetch t+2 into A while computing t+1 from B
    if (t + 2 < NT) {
      LOADK(t + 2, kA0, kA1, kA2, kA3);
      LOADV(t + 2, vA0, vA1, vA2, vA3);
    }
    QK(kB0, kB1, kB2, kB3, sL, sH);
    SOFTPV(sL, sH, vB0, vB1, vB2, vB3);
  }

  // denominator: fold the two hi-slices (16 keys each) of this key-half
  lsL += __shfl_xor(lsL, 32);
  lsH += __shfl_xor(lsH, 32);

  // ---- key-half merge: plain addition (no-max softmax partials are exact).
  const int mi = (g * 64 + lane) * 36;
  __syncthreads();  // all waves done with their loops
  if (kh) {
#pragma unroll
    for (int r = 0; r < 4; ++r) {
      *(f32x4*)(mrg + mi + r * 4) =
          f32x4{o00[r * 4], o00[r * 4 + 1], o00[r * 4 + 2], o00[r * 4 + 3]};
      *(f32x4*)(mrg + mi + 16 + r * 4) =
          f32x4{o01[r * 4], o01[r * 4 + 1], o01[r * 4 + 2], o01[r * 4 + 3]};
    }
    mrg[mi + 32] = lsL;
    mrg[mi + 33] = lsH;
  }
  __syncthreads();
  float rlL = 0.f, rlH = 0.f;
  if (!kh) {
#pragma unroll
    for (int r = 0; r < 16; ++r) {
      o00[r] += mrg[mi + r];
      o01[r] += mrg[mi + 16 + r];
    }
    rlL = 1.f / (lsL + mrg[mi + 32]);
    rlH = 1.f / (lsH + mrg[mi + 33]);
  }
  __syncthreads();
  if (kh) {
#pragma unroll
    for (int r = 0; r < 4; ++r) {
      *(f32x4*)(mrg + mi + r * 4) =
          f32x4{o10[r * 4], o10[r * 4 + 1], o10[r * 4 + 2], o10[r * 4 + 3]};
      *(f32x4*)(mrg + mi + 16 + r * 4) =
          f32x4{o11[r * 4], o11[r * 4 + 1], o11[r * 4 + 2], o11[r * 4 + 3]};
    }
  }
  __syncthreads();
  if (!kh) {
#pragma unroll
    for (int r = 0; r < 16; ++r) {
      o10[r] += mrg[mi + r];
      o11[r] += mrg[mi + 16 + r];
    }
    // write out: q row = q0 + qh*32 + qi; dk = dkh*32 + rr*8 + hi*4 + e
    short* OpL = O + ((size_t)(b * S_ + q0 + qi)) * E_ + h * DK_;
    short* OpH = O + ((size_t)(b * S_ + q0 + 32 + qi)) * E_ + h * DK_;
#pragma unroll
    for (int rr = 0; rr < 4; ++rr) {
      s16x4 vL0, vL1, vH0, vH1;
#pragma unroll
      for (int e = 0; e < 4; ++e) {
        vL0[e] = f2bf(o00[rr * 4 + e] * rlL);
        vL1[e] = f2bf(o10[rr * 4 + e] * rlL);
        vH0[e] = f2bf(o01[rr * 4 + e] * rlH);
        vH1[e] = f2bf(o11[rr * 4 + e] * rlH);
      }
      *(s16x4*)(OpL + rr * 8 + hi * 4) = vL0;
      *(s16x4*)(OpL + 32 + rr * 8 + hi * 4) = vL1;
      *(s16x4*)(OpH + rr * 8 + hi * 4) = vH0;
      *(s16x4*)(OpH + 32 + rr * 8 + hi * 4) = vH1;
    }
  }
#undef LOADK
#undef LOADV
#undef QK
#undef SOFTPV
}

// ---------------- launch ----------------
extern "C" void kernel_launch(void* const* d_in, const int* in_sizes, int n_in,
                              void* d_out, int out_size, void* d_ws, size_t ws_size,
                              hipStream_t stream) {
  const float* query  = (const float*)d_in[0];
  const float* key_in = (const float*)d_in[1];
  const float* value  = (const float*)d_in[2];
  const float* Wq = (const float*)d_in[3];
  const float* bq = (const float*)d_in[4];
  const float* Wk = (const float*)d_in[5];
  const float* bk = (const float*)d_in[6];
  const float* Wv = (const float*)d_in[7];
  const float* bv = (const float*)d_in[8];
  const float* Wo = (const float*)d_in[9];
  const float* bo = (const float*)d_in[10];
  float* out = (float*)d_out;

  const size_t NA = (size_t)M_ * E_;  // 4,194,304
  short* ws  = (short*)d_ws;
  short* Xq  = ws;                    // bf16 activations (x3 contiguous)
  short* Wt  = Xq + 3 * NA;           // bf16 W^T, q/k/v/o fused [4E][E]
  short* Wot = Wt + 3 * E_ * E_;
  short* Qb  = Wt + 4 * E_ * E_;      // bf16 [B,H,S,DK] (pre-scaled log2e)
  short* Kb  = Qb + NA;               // bf16 [B,H,S,DK]
  short* Vtb = Kb + NA;               // bf16 [B,H,DK,S]
  short* AO  = Vtb + NA;              // bf16 attn out [B,S,E]
  short* Xk  = Xq + NA;
  short* Xv  = Xk + NA;

  conv_bf16_all<<<dim3(NA / 1024, 3), 256, 0, stream>>>(
      query, key_in, value, Xq, (int)(NA / 4));
  conv_wT_all<<<dim3(E_ * E_ / 256, 4), 256, 0, stream>>>(Wq, Wk, Wv, Wo, Wt);

  gemm_qkv<<<dim3(M_ / 128, E_ / 128, 3), 256, 0, stream>>>(
      Xq, Xk, Xv, Wt, bq, bk, bv, Qb, Kb, Vtb);
  attn_fwd<<<dim3(S_ / 256, B_ * H_), 512, 0, stream>>>(Qb, Kb, Vtb, AO);
  gemm_out<<<dim3(M_ / 128, E_ / 128), 256, 0, stream>>>(AO, Wot, bo, out);
}

// Round 13
// 148.200 us; speedup vs baseline: 1.2758x; 1.2758x over previous
//
#include <hip/hip_runtime.h>
#include <hip/hip_bf16.h>

#define B_  2
#define S_  4096
#define E_  512
#define H_  8
#define DK_ 64
#define M_  8192  // B_*S_

typedef float f32x4  __attribute__((ext_vector_type(4)));
typedef float f32x16 __attribute__((ext_vector_type(16)));
typedef short s16x8  __attribute__((ext_vector_type(8)));
typedef short s16x4  __attribute__((ext_vector_type(4)));

static __device__ __forceinline__ short f2bf(float x) {
  __hip_bfloat16 h = __float2bfloat16(x);
  return __builtin_bit_cast(short, h);
}

static __device__ __forceinline__ f32x4 mfma32(s16x8 a, s16x8 b, f32x4 c) {
  return __builtin_amdgcn_mfma_f32_16x16x32_bf16(a, b, c, 0, 0, 0);
}

static __device__ __forceinline__ f32x16 mfma3232(s16x8 a, s16x8 b, f32x16 c) {
  return __builtin_amdgcn_mfma_f32_32x32x16_bf16(a, b, c, 0, 0, 0);
}

// 2^x. Compiler intrinsic (proper hazard handling — raw inline-asm v_exp_f32
// was round-3's correctness bug). Fallback: e^(x ln2) via __expf.
static __device__ __forceinline__ float fastexp2(float x) {
#if __has_builtin(__builtin_amdgcn_exp2f)
  return __builtin_amdgcn_exp2f(x);
#else
  return __expf(x * 0.69314718056f);
#endif
}

static __device__ __forceinline__ void gload_lds16(const void* g, void* l) {
  __builtin_amdgcn_global_load_lds(
      (const __attribute__((address_space(1))) unsigned int*)g,
      (__attribute__((address_space(3))) unsigned int*)l, 16, 0, 0);
}

// W [E][E] f32 row-major -> Wt bf16 [N=E][K=E] (transposed); y selects W.
__global__ __launch_bounds__(256) void conv_wT_all(
    const float* __restrict__ Wq, const float* __restrict__ Wk,
    const float* __restrict__ Wv, const float* __restrict__ Wo,
    short* __restrict__ Wt) {
  const float* W = (blockIdx.y == 0) ? Wq
                   : ((blockIdx.y == 1) ? Wk : ((blockIdx.y == 2) ? Wv : Wo));
  short* o = Wt + (size_t)blockIdx.y * (E_ * E_);
  int idx = blockIdx.x * 256 + threadIdx.x;
  int j = idx >> 9, k = idx & 511;
  o[idx] = f2bf(W[(size_t)k * E_ + j]);
}

// ------- GEMM core (bf16 A): 2-phase dbuf, BK=32, frag-gathered LDS -------
static __device__ __forceinline__ void gemm_core_512(
    const short* __restrict__ A, const short* __restrict__ Bt,
    short* As, short* Bs, int tm, int tn, f32x4 acc[4][4]) {
  const int tid = threadIdx.x;
  const int wave = tid >> 6, lane = tid & 63;
  const int c = lane & 15, g = lane >> 4;
  int fOff[2];
#pragma unroll
  for (int r = 0; r < 2; ++r) {
    const int f = wave * 2 + r;  // frag 0..7
    fOff[r] = ((f >> 2) * 64 + (f & 3) * 16 + c) * 512 + g * 8;
  }
  auto stg = [&](int p, int b) {
#pragma unroll
    for (int r = 0; r < 2; ++r) {
      const int f = wave * 2 + r;
      gload_lds16(A + (size_t)tm * 512 + p * 32 + fOff[r],
                  (char*)As + b * 8192 + f * 1024);
      gload_lds16(Bt + (size_t)tn * 512 + p * 32 + fOff[r],
                  (char*)Bs + b * 8192 + f * 1024);
    }
  };
  stg(0, 0);
  __syncthreads();
  for (int p = 0; p < 16; ++p) {
    if (p + 1 < 16) stg(p + 1, (p + 1) & 1);  // overlaps compute below
    const short* Ac = As + (p & 1) * 4096;
    const short* Bc = Bs + (p & 1) * 4096;
    s16x8 af[4], bfr[4];
#pragma unroll
    for (int i = 0; i < 4; ++i)
      af[i] = *(const s16x8*)(Ac + ((wave >> 1) * 4 + i) * 512 + lane * 8);
#pragma unroll
    for (int j = 0; j < 4; ++j)
      bfr[j] = *(const s16x8*)(Bc + ((wave & 1) * 4 + j) * 512 + lane * 8);
#pragma unroll
    for (int i = 0; i < 4; ++i)
#pragma unroll
      for (int j = 0; j < 4; ++j)
        acc[i][j] = mfma32(af[i], bfr[j], acc[i][j]);
    __syncthreads();
  }
}

// ------- GEMM core (f32 A, fused conversion): T14 reg-staged A ------------
// A loads (f32) issue BEFORE compute, cvt+ds_write lands AFTER (compiler
// places the s_waitcnt at the use). B (bf16 weights) stays on gload_lds.
// A bf16 values identical to the old conv pass (same rounding, same sums).
static __device__ __forceinline__ void gemm_core_f32A(
    const float* __restrict__ A, const short* __restrict__ Bt,
    short* As, short* Bs, int tm, int tn, f32x4 acc[4][4]) {
  const int tid = threadIdx.x;
  const int wave = tid >> 6, lane = tid & 63;
  const int c = lane & 15, g = lane >> 4;
  int fOff[2];
#pragma unroll
  for (int r = 0; r < 2; ++r) {
    const int f = wave * 2 + r;
    fOff[r] = ((f >> 2) * 64 + (f & 3) * 16 + c) * 512 + g * 8;
  }
  auto stgB = [&](int p, int b) {
#pragma unroll
    for (int r = 0; r < 2; ++r)
      gload_lds16(Bt + (size_t)tn * 512 + p * 32 + fOff[r],
                  (char*)Bs + b * 8192 + (wave * 2 + r) * 1024);
  };
  float4 a0[2], a1[2];
  auto ldA = [&](int p) {
#pragma unroll
    for (int r = 0; r < 2; ++r) {
      const float* ap = A + (size_t)tm * 512 + p * 32 + fOff[r];
      a0[r] = *(const float4*)ap;
      a1[r] = *(const float4*)(ap + 4);
    }
  };
  auto wrA = [&](int b) {
#pragma unroll
    for (int r = 0; r < 2; ++r) {
      s16x8 w;
      w[0] = f2bf(a0[r].x); w[1] = f2bf(a0[r].y);
      w[2] = f2bf(a0[r].z); w[3] = f2bf(a0[r].w);
      w[4] = f2bf(a1[r].x); w[5] = f2bf(a1[r].y);
      w[6] = f2bf(a1[r].z); w[7] = f2bf(a1[r].w);
      *(s16x8*)((char*)As + b * 8192 + (wave * 2 + r) * 1024 + lane * 16) = w;
    }
  };
  ldA(0); stgB(0, 0); wrA(0);
  __syncthreads();
  for (int p = 0; p < 16; ++p) {
    if (p + 1 < 16) { ldA(p + 1); stgB(p + 1, (p + 1) & 1); }
    const short* Ac = As + (p & 1) * 4096;
    const short* Bc = Bs + (p & 1) * 4096;
    s16x8 af[4], bfr[4];
#pragma unroll
    for (int i = 0; i < 4; ++i)
      af[i] = *(const s16x8*)(Ac + ((wave >> 1) * 4 + i) * 512 + lane * 8);
#pragma unroll
    for (int j = 0; j < 4; ++j)
      bfr[j] = *(const s16x8*)(Bc + ((wave & 1) * 4 + j) * 512 + lane * 8);
#pragma unroll
    for (int i = 0; i < 4; ++i)
#pragma unroll
      for (int j = 0; j < 4; ++j)
        acc[i][j] = mfma32(af[i], bfr[j], acc[i][j]);
    if (p + 1 < 16) wrA((p + 1) & 1);  // into the buffer freed last barrier
    __syncthreads();
  }
}

// QKV projections from the ORIGINAL f32 inputs (conv pass fused away).
// Epilogue: +bias, ->bf16, scatter Q/K to [B,H,S,DK], V to V^T [B,H,DK,S].
// Q pre-scaled by log2(e): attention uses 2^s (softmax ratio-invariant).
__global__ __launch_bounds__(256) void gemm_qkv(
    const float* __restrict__ Xq, const float* __restrict__ Xk,
    const float* __restrict__ Xv, const short* __restrict__ Wt,
    const float* __restrict__ bq, const float* __restrict__ bk,
    const float* __restrict__ bv,
    short* __restrict__ Qo, short* __restrict__ Ko, short* __restrict__ Vto) {
  __shared__ __align__(16) short As[2 * 4096];
  __shared__ __align__(16) short Bs[2 * 4096];
  const int z = blockIdx.z;
  const float* A = (z == 0) ? Xq : ((z == 1) ? Xk : Xv);
  const short* Bt = Wt + z * (E_ * E_);
  const float* bias = (z == 0) ? bq : ((z == 1) ? bk : bv);
  const int tm = blockIdx.x * 128, tn = blockIdx.y * 128;
  f32x4 acc[4][4] = {};
  gemm_core_f32A(A, Bt, As, Bs, tm, tn, acc);

  const int tid = threadIdx.x;
  const int wave = tid >> 6, lane = tid & 63;
  const int wm = (wave >> 1) * 64, wn = (wave & 1) * 64;
  const int c = lane & 15, g = lane >> 4;
#pragma unroll
  for (int i = 0; i < 4; ++i) {
#pragma unroll
    for (int j = 0; j < 4; ++j) {
      const int gc = tn + wn + j * 16 + c;
      const float bb = bias[gc];
      const int h = gc >> 6, dk = gc & 63;
      if (z == 2) {
        const int gr0 = tm + wm + i * 16 + g * 4;
        const int b = gr0 >> 12, s0 = gr0 & 4095;
        s16x4 v4;
#pragma unroll
        for (int r = 0; r < 4; ++r) v4[r] = f2bf(acc[i][j][r] + bb);
        *(s16x4*)&Vto[(size_t)((b * H_ + h) * DK_ + dk) * S_ + s0] = v4;
      } else {
#pragma unroll
        for (int r = 0; r < 4; ++r) {
          const int gr = tm + wm + i * 16 + g * 4 + r;
          const int b = gr >> 12, s = gr & 4095;
          float v = acc[i][j][r] + bb;
          if (z == 0) v *= 1.44269504f;  // Q *= log2(e)
          const short hv = f2bf(v);
          if (z == 1)
            Ko[(size_t)((b * H_ + h) * S_ + s) * DK_ + dk] = hv;
          else
            Qo[(size_t)((b * H_ + h) * S_ + s) * DK_ + dk] = hv;
        }
      }
    }
  }
}

// Output projection: out = AO(bf16) @ Wo + bo, f32 row-major.
__global__ __launch_bounds__(256) void gemm_out(
    const short* __restrict__ AO, const short* __restrict__ Wot,
    const float* __restrict__ bo, float* __restrict__ out) {
  __shared__ __align__(16) short As[2 * 4096];
  __shared__ __align__(16) short Bs[2 * 4096];
  const int tm = blockIdx.x * 128, tn = blockIdx.y * 128;
  f32x4 acc[4][4] = {};
  gemm_core_512(AO, Wot, As, Bs, tm, tn, acc);

  const int tid = threadIdx.x;
  const int wave = tid >> 6, lane = tid & 63;
  const int wm = (wave >> 1) * 64, wn = (wave & 1) * 64;
  const int c = lane & 15, g = lane >> 4;
#pragma unroll
  for (int i = 0; i < 4; ++i) {
#pragma unroll
    for (int j = 0; j < 4; ++j) {
      const int gc = tn + wn + j * 16 + c;
      const float bb = bo[gc];
#pragma unroll
      for (int r = 0; r < 4; ++r) {
        const int gr = tm + wm + i * 16 + g * 4 + r;
        out[(size_t)gr * E_ + gc] = acc[i][j][r] + bb;
      }
    }
  }
}

// ---- flash attention: r11 structure, TWO barrier domains per CU ----------
// 4 waves/block (2 q-groups x 2 key-halves), 128 q/block, grid 32x16 = 512
// blocks = 2 blocks/CU. Same total waves & 2x fragment reuse as r11, but
// the two co-resident blocks have INDEPENDENT barriers -> they drift out of
// phase and one block's exp/VALU burst overlaps the other's MFMA/LDS burst
// (r7 showed lockstep = serialized pipe sum; r12 showed reg-direct loses to
// LDS staging). Each wave stages 2 K-frags + 2 V-frags (r7 pattern);
// counted-vmcnt barrier waits the PREVIOUS window's 4 loads (vmcnt(4)).
// No-max softmax (Q pre-scaled by log2 e), per-lane l sums, key-half merge.
__global__ __launch_bounds__(256, 2) void attn_fwd(
    const short* __restrict__ Q, const short* __restrict__ K,
    const short* __restrict__ Vt, short* __restrict__ O) {
  __shared__ __align__(16) char lds[49152];  // K 3buf | V 3buf; merge overlay
  const int tid = threadIdx.x;
  const int wave = tid >> 6, lane = tid & 63;
  const int g = wave >> 1, kh = wave & 1;
  const int qi = lane & 31, hi = lane >> 5;
  const int bh = blockIdx.y;
  const int b = bh >> 3, h = bh & 7;
  const int q0 = blockIdx.x * 128 + g * 64;
  const short* Qp = Q + (size_t)bh * S_ * DK_;
  const short* Kp = K + (size_t)bh * S_ * DK_;
  const short* Vp = Vt + (size_t)bh * DK_ * S_;

  s16x8 qfL[4], qfH[4];
#pragma unroll
  for (int s = 0; s < 4; ++s) {
    qfL[s] = *(const s16x8*)(Qp + (size_t)(q0 + qi) * DK_ + s * 16 + hi * 8);
    qfH[s] = *(const s16x8*)(Qp + (size_t)(q0 + 32 + qi) * DK_ + s * 16 + hi * 8);
  }

  f32x16 o00 = {}, o01 = {}, o10 = {}, o11 = {};  // o[dkh][qh]
  float lsL = 0.f, lsH = 0.f;                     // denominator partials

  // per-lane gather offsets: wave stages frags f = wave*2, wave*2+1
  int kOffL[2], vOffL[2];
#pragma unroll
  for (int r = 0; r < 2; ++r) {
    const int f = wave * 2 + r;            // 0..7
    const int row = (f >> 2) * 32 + qi;    // K source row (pre-tau)
    const int srow = (row & 32) | ((row & 8) << 1) | ((row & 4) << 1) |
                     ((row & 16) >> 2) | (row & 3);  // tau permute
    kOffL[r] = srow * DK_ + (f & 3) * 16 + hi * 8;
    vOffL[r] = ((f >> 2) * 32 + qi) * S_ + ((f >> 1) & 1) * 32 +
               (f & 1) * 16 + hi * 8;
  }

  // stage tile kt: K frags -> lds[(kt%3)*8K], V frags -> lds[24K+(kt%3)*8K]
  auto stage = [&](int kt) {
#pragma unroll
    for (int r = 0; r < 2; ++r) {
      const int f = wave * 2 + r;
      gload_lds16(Kp + (size_t)kt * 64 * DK_ + kOffL[r],
                  lds + (kt % 3) * 8192 + f * 1024);
      gload_lds16(Vp + (size_t)kt * 64 + vOffL[r],
                  lds + 24576 + (kt % 3) * 8192 + f * 1024);
    }
  };

  // counted-vmcnt barrier: previous window's 4 loads complete; the 4 just
  // issued stay in flight across the barrier.
  auto bar4 = [&]() {
    asm volatile("s_waitcnt vmcnt(4) lgkmcnt(0)" ::: "memory");
    __builtin_amdgcn_s_barrier();
  };
  auto bar0 = [&]() {
    asm volatile("s_waitcnt vmcnt(0) lgkmcnt(0)" ::: "memory");
    __builtin_amdgcn_s_barrier();
  };

  const int lbK = kh * 4096 + (lane << 4);

  auto qk = [&](int t, f32x16& sL, f32x16& sH) {
    const char* Kc = lds + (t % 3) * 8192 + lbK;
    f32x16 a = {}, c = {};
    __builtin_amdgcn_s_setprio(1);
#pragma unroll
    for (int s = 0; s < 4; ++s) {
      s16x8 ka = *(const s16x8*)(Kc + s * 1024);
      a = mfma3232(ka, qfL[s], a);
      c = mfma3232(ka, qfH[s], c);
    }
    __builtin_amdgcn_s_setprio(0);
    sL = a; sH = c;
  };

  auto softpv = [&](const f32x16& sL, const f32x16& sH, int t) {
    const char* Vc = lds + 24576 + (t % 3) * 8192 + kh * 2048 + (lane << 4);
    float pL[16], pH[16];
#pragma unroll
    for (int r = 0; r < 16; ++r) { pL[r] = fastexp2(sL[r]); pH[r] = fastexp2(sH[r]); }
    float aL = 0.f, aH = 0.f;
#pragma unroll
    for (int r = 0; r < 16; ++r) { aL += pL[r]; aH += pH[r]; }
    lsL += aL; lsH += aH;
    s16x8 pbL[2], pbH[2];
#pragma unroll
    for (int ks = 0; ks < 2; ++ks)
#pragma unroll
      for (int j = 0; j < 8; ++j) {
        const int r = (j & 3) | (ks << 2) | ((j >> 2) << 3);
        pbL[ks][j] = f2bf(pL[r]);
        pbH[ks][j] = f2bf(pH[r]);
      }
    __builtin_amdgcn_s_setprio(1);
#pragma unroll
    for (int ks = 0; ks < 2; ++ks) {
      s16x8 va0 = *(const s16x8*)(Vc + ks * 1024);          // dk 0-31
      s16x8 va1 = *(const s16x8*)(Vc + 4096 + ks * 1024);   // dk 32-63
      o00 = mfma3232(va0, pbL[ks], o00);
      o01 = mfma3232(va0, pbH[ks], o01);
      o10 = mfma3232(va1, pbL[ks], o10);
      o11 = mfma3232(va1, pbH[ks], o11);
    }
    __builtin_amdgcn_s_setprio(0);
  };

  const int NT = S_ / 64;
  f32x16 sA0, sA1, sB0, sB1;

  stage(0);
  stage(1);
  bar4();
  qk(0, sA0, sA1);

  for (int t = 0; t < NT; t += 2) {
    if (t + 2 < NT) { stage(t + 2); bar4(); } else { bar0(); }
    qk(t + 1, sB0, sB1);
    softpv(sA0, sA1, t);
    if (t + 3 < NT) { stage(t + 3); bar4(); } else { bar0(); }
    if (t + 2 < NT) qk(t + 2, sA0, sA1);
    softpv(sB0, sB1, t + 1);
  }

  lsL += __shfl_xor(lsL, 32);
  lsH += __shfl_xor(lsH, 32);

  // ---- key-half merge: plain addition (no-max softmax partials exact) ----
  float* mrg = (float*)lds;
  const int mi = (g * 64 + lane) * 36;
  __syncthreads();
  if (kh) {
#pragma unroll
    for (int r = 0; r < 4; ++r) {
      *(f32x4*)(mrg + mi + r * 4) =
          f32x4{o00[r * 4], o00[r * 4 + 1], o00[r * 4 + 2], o00[r * 4 + 3]};
      *(f32x4*)(mrg + mi + 16 + r * 4) =
          f32x4{o01[r * 4], o01[r * 4 + 1], o01[r * 4 + 2], o01[r * 4 + 3]};
    }
    mrg[mi + 32] = lsL;
    mrg[mi + 33] = lsH;
  }
  __syncthreads();
  float rlL = 0.f, rlH = 0.f;
  if (!kh) {
#pragma unroll
    for (int r = 0; r < 16; ++r) {
      o00[r] += mrg[mi + r];
      o01[r] += mrg[mi + 16 + r];
    }
    rlL = 1.f / (lsL + mrg[mi + 32]);
    rlH = 1.f / (lsH + mrg[mi + 33]);
  }
  __syncthreads();
  if (kh) {
#pragma unroll
    for (int r = 0; r < 4; ++r) {
      *(f32x4*)(mrg + mi + r * 4) =
          f32x4{o10[r * 4], o10[r * 4 + 1], o10[r * 4 + 2], o10[r * 4 + 3]};
      *(f32x4*)(mrg + mi + 16 + r * 4) =
          f32x4{o11[r * 4], o11[r * 4 + 1], o11[r * 4 + 2], o11[r * 4 + 3]};
    }
  }
  __syncthreads();
  if (!kh) {
#pragma unroll
    for (int r = 0; r < 16; ++r) {
      o10[r] += mrg[mi + r];
      o11[r] += mrg[mi + 16 + r];
    }
    short* OpL = O + ((size_t)(b * S_ + q0 + qi)) * E_ + h * DK_;
    short* OpH = O + ((size_t)(b * S_ + q0 + 32 + qi)) * E_ + h * DK_;
#pragma unroll
    for (int rr = 0; rr < 4; ++rr) {
      s16x4 vL0, vL1, vH0, vH1;
#pragma unroll
      for (int e = 0; e < 4; ++e) {
        vL0[e] = f2bf(o00[rr * 4 + e] * rlL);
        vL1[e] = f2bf(o10[rr * 4 + e] * rlL);
        vH0[e] = f2bf(o01[rr * 4 + e] * rlH);
        vH1[e] = f2bf(o11[rr * 4 + e] * rlH);
      }
      *(s16x4*)(OpL + rr * 8 + hi * 4) = vL0;
      *(s16x4*)(OpL + 32 + rr * 8 + hi * 4) = vL1;
      *(s16x4*)(OpH + rr * 8 + hi * 4) = vH0;
      *(s16x4*)(OpH + 32 + rr * 8 + hi * 4) = vH1;
    }
  }
}

// ---------------- launch ----------------
extern "C" void kernel_launch(void* const* d_in, const int* in_sizes, int n_in,
                              void* d_out, int out_size, void* d_ws, size_t ws_size,
                              hipStream_t stream) {
  const float* query  = (const float*)d_in[0];
  const float* key_in = (const float*)d_in[1];
  const float* value  = (const float*)d_in[2];
  const float* Wq = (const float*)d_in[3];
  const float* bq = (const float*)d_in[4];
  const float* Wk = (const float*)d_in[5];
  const float* bk = (const float*)d_in[6];
  const float* Wv = (const float*)d_in[7];
  const float* bv = (const float*)d_in[8];
  const float* Wo = (const float*)d_in[9];
  const float* bo = (const float*)d_in[10];
  float* out = (float*)d_out;

  const size_t NA = (size_t)M_ * E_;  // 4,194,304
  short* ws  = (short*)d_ws;
  short* Wt  = ws;                    // bf16 W^T, q/k/v/o fused [4E][E]
  short* Wot = Wt + 3 * E_ * E_;
  short* Qb  = Wt + 4 * E_ * E_;      // bf16 [B,H,S,DK] (pre-scaled log2e)
  short* Kb  = Qb + NA;               // bf16 [B,H,S,DK]
  short* Vtb = Kb + NA;               // bf16 [B,H,DK,S]
  short* AO  = Vtb + NA;              // bf16 attn out [B,S,E]

  conv_wT_all<<<dim3(E_ * E_ / 256, 4), 256, 0, stream>>>(Wq, Wk, Wv, Wo, Wt);

  gemm_qkv<<<dim3(M_ / 128, E_ / 128, 3), 256, 0, stream>>>(
      query, key_in, value, Wt, bq, bk, bv, Qb, Kb, Vtb);
  attn_fwd<<<dim3(S_ / 128, B_ * H_), 256, 0, stream>>>(Qb, Kb, Vtb, AO);
  gemm_out<<<dim3(M_ / 128, E_ / 128), 256, 0, stream>>>(AO, Wot, bo, out);
}

// Round 14
// 144.671 us; speedup vs baseline: 1.3070x; 1.0244x over previous
//
#include <hip/hip_runtime.h>
#include <hip/hip_bf16.h>

#define B_  2
#define S_  4096
#define E_  512
#define H_  8
#define DK_ 64
#define M_  8192  // B_*S_

typedef float f32x4  __attribute__((ext_vector_type(4)));
typedef float f32x16 __attribute__((ext_vector_type(16)));
typedef short s16x8  __attribute__((ext_vector_type(8)));
typedef short s16x4  __attribute__((ext_vector_type(4)));

static __device__ __forceinline__ short f2bf(float x) {
  __hip_bfloat16 h = __float2bfloat16(x);
  return __builtin_bit_cast(short, h);
}

static __device__ __forceinline__ f32x4 mfma32(s16x8 a, s16x8 b, f32x4 c) {
  return __builtin_amdgcn_mfma_f32_16x16x32_bf16(a, b, c, 0, 0, 0);
}

static __device__ __forceinline__ f32x16 mfma3232(s16x8 a, s16x8 b, f32x16 c) {
  return __builtin_amdgcn_mfma_f32_32x32x16_bf16(a, b, c, 0, 0, 0);
}

// 2^x. Compiler intrinsic (proper hazard handling — raw inline-asm v_exp_f32
// was round-3's correctness bug). Fallback: e^(x ln2) via __expf.
static __device__ __forceinline__ float fastexp2(float x) {
#if __has_builtin(__builtin_amdgcn_exp2f)
  return __builtin_amdgcn_exp2f(x);
#else
  return __expf(x * 0.69314718056f);
#endif
}

static __device__ __forceinline__ void gload_lds16(const void* g, void* l) {
  __builtin_amdgcn_global_load_lds(
      (const __attribute__((address_space(1))) unsigned int*)g,
      (__attribute__((address_space(3))) unsigned int*)l, 16, 0, 0);
}

// W [E][E] f32 row-major -> Wt bf16 [N=E][K=E] (transposed); y selects W.
__global__ __launch_bounds__(256) void conv_wT_all(
    const float* __restrict__ Wq, const float* __restrict__ Wk,
    const float* __restrict__ Wv, const float* __restrict__ Wo,
    short* __restrict__ Wt) {
  const float* W = (blockIdx.y == 0) ? Wq
                   : ((blockIdx.y == 1) ? Wk : ((blockIdx.y == 2) ? Wv : Wo));
  short* o = Wt + (size_t)blockIdx.y * (E_ * E_);
  int idx = blockIdx.x * 256 + threadIdx.x;
  int j = idx >> 9, k = idx & 511;
  o[idx] = f2bf(W[(size_t)k * E_ + j]);
}

// ------- GEMM core (bf16 A): 2-phase dbuf, BK=32, frag-gathered LDS -------
static __device__ __forceinline__ void gemm_core_512(
    const short* __restrict__ A, const short* __restrict__ Bt,
    short* As, short* Bs, int tm, int tn, f32x4 acc[4][4]) {
  const int tid = threadIdx.x;
  const int wave = tid >> 6, lane = tid & 63;
  const int c = lane & 15, g = lane >> 4;
  int fOff[2];
#pragma unroll
  for (int r = 0; r < 2; ++r) {
    const int f = wave * 2 + r;  // frag 0..7
    fOff[r] = ((f >> 2) * 64 + (f & 3) * 16 + c) * 512 + g * 8;
  }
  auto stg = [&](int p, int b) {
#pragma unroll
    for (int r = 0; r < 2; ++r) {
      const int f = wave * 2 + r;
      gload_lds16(A + (size_t)tm * 512 + p * 32 + fOff[r],
                  (char*)As + b * 8192 + f * 1024);
      gload_lds16(Bt + (size_t)tn * 512 + p * 32 + fOff[r],
                  (char*)Bs + b * 8192 + f * 1024);
    }
  };
  stg(0, 0);
  __syncthreads();
  for (int p = 0; p < 16; ++p) {
    if (p + 1 < 16) stg(p + 1, (p + 1) & 1);  // overlaps compute below
    const short* Ac = As + (p & 1) * 4096;
    const short* Bc = Bs + (p & 1) * 4096;
    s16x8 af[4], bfr[4];
#pragma unroll
    for (int i = 0; i < 4; ++i)
      af[i] = *(const s16x8*)(Ac + ((wave >> 1) * 4 + i) * 512 + lane * 8);
#pragma unroll
    for (int j = 0; j < 4; ++j)
      bfr[j] = *(const s16x8*)(Bc + ((wave & 1) * 4 + j) * 512 + lane * 8);
#pragma unroll
    for (int i = 0; i < 4; ++i)
#pragma unroll
      for (int j = 0; j < 4; ++j)
        acc[i][j] = mfma32(af[i], bfr[j], acc[i][j]);
    __syncthreads();
  }
}

// ------- GEMM core (f32 A, fused conversion): T14 reg-staged A ------------
static __device__ __forceinline__ void gemm_core_f32A(
    const float* __restrict__ A, const short* __restrict__ Bt,
    short* As, short* Bs, int tm, int tn, f32x4 acc[4][4]) {
  const int tid = threadIdx.x;
  const int wave = tid >> 6, lane = tid & 63;
  const int c = lane & 15, g = lane >> 4;
  int fOff[2];
#pragma unroll
  for (int r = 0; r < 2; ++r) {
    const int f = wave * 2 + r;
    fOff[r] = ((f >> 2) * 64 + (f & 3) * 16 + c) * 512 + g * 8;
  }
  auto stgB = [&](int p, int b) {
#pragma unroll
    for (int r = 0; r < 2; ++r)
      gload_lds16(Bt + (size_t)tn * 512 + p * 32 + fOff[r],
                  (char*)Bs + b * 8192 + (wave * 2 + r) * 1024);
  };
  float4 a0[2], a1[2];
  auto ldA = [&](int p) {
#pragma unroll
    for (int r = 0; r < 2; ++r) {
      const float* ap = A + (size_t)tm * 512 + p * 32 + fOff[r];
      a0[r] = *(const float4*)ap;
      a1[r] = *(const float4*)(ap + 4);
    }
  };
  auto wrA = [&](int b) {
#pragma unroll
    for (int r = 0; r < 2; ++r) {
      s16x8 w;
      w[0] = f2bf(a0[r].x); w[1] = f2bf(a0[r].y);
      w[2] = f2bf(a0[r].z); w[3] = f2bf(a0[r].w);
      w[4] = f2bf(a1[r].x); w[5] = f2bf(a1[r].y);
      w[6] = f2bf(a1[r].z); w[7] = f2bf(a1[r].w);
      *(s16x8*)((char*)As + b * 8192 + (wave * 2 + r) * 1024 + lane * 16) = w;
    }
  };
  ldA(0); stgB(0, 0); wrA(0);
  __syncthreads();
  for (int p = 0; p < 16; ++p) {
    if (p + 1 < 16) { ldA(p + 1); stgB(p + 1, (p + 1) & 1); }
    const short* Ac = As + (p & 1) * 4096;
    const short* Bc = Bs + (p & 1) * 4096;
    s16x8 af[4], bfr[4];
#pragma unroll
    for (int i = 0; i < 4; ++i)
      af[i] = *(const s16x8*)(Ac + ((wave >> 1) * 4 + i) * 512 + lane * 8);
#pragma unroll
    for (int j = 0; j < 4; ++j)
      bfr[j] = *(const s16x8*)(Bc + ((wave & 1) * 4 + j) * 512 + lane * 8);
#pragma unroll
    for (int i = 0; i < 4; ++i)
#pragma unroll
      for (int j = 0; j < 4; ++j)
        acc[i][j] = mfma32(af[i], bfr[j], acc[i][j]);
    if (p + 1 < 16) wrA((p + 1) & 1);  // into the buffer freed last barrier
    __syncthreads();
  }
}

// QKV projections from the ORIGINAL f32 inputs (conv pass fused away).
__global__ __launch_bounds__(256) void gemm_qkv(
    const float* __restrict__ Xq, const float* __restrict__ Xk,
    const float* __restrict__ Xv, const short* __restrict__ Wt,
    const float* __restrict__ bq, const float* __restrict__ bk,
    const float* __restrict__ bv,
    short* __restrict__ Qo, short* __restrict__ Ko, short* __restrict__ Vto) {
  __shared__ __align__(16) short As[2 * 4096];
  __shared__ __align__(16) short Bs[2 * 4096];
  const int z = blockIdx.z;
  const float* A = (z == 0) ? Xq : ((z == 1) ? Xk : Xv);
  const short* Bt = Wt + z * (E_ * E_);
  const float* bias = (z == 0) ? bq : ((z == 1) ? bk : bv);
  const int tm = blockIdx.x * 128, tn = blockIdx.y * 128;
  f32x4 acc[4][4] = {};
  gemm_core_f32A(A, Bt, As, Bs, tm, tn, acc);

  const int tid = threadIdx.x;
  const int wave = tid >> 6, lane = tid & 63;
  const int wm = (wave >> 1) * 64, wn = (wave & 1) * 64;
  const int c = lane & 15, g = lane >> 4;
#pragma unroll
  for (int i = 0; i < 4; ++i) {
#pragma unroll
    for (int j = 0; j < 4; ++j) {
      const int gc = tn + wn + j * 16 + c;
      const float bb = bias[gc];
      const int h = gc >> 6, dk = gc & 63;
      if (z == 2) {
        const int gr0 = tm + wm + i * 16 + g * 4;
        const int b = gr0 >> 12, s0 = gr0 & 4095;
        s16x4 v4;
#pragma unroll
        for (int r = 0; r < 4; ++r) v4[r] = f2bf(acc[i][j][r] + bb);
        *(s16x4*)&Vto[(size_t)((b * H_ + h) * DK_ + dk) * S_ + s0] = v4;
      } else {
#pragma unroll
        for (int r = 0; r < 4; ++r) {
          const int gr = tm + wm + i * 16 + g * 4 + r;
          const int b = gr >> 12, s = gr & 4095;
          float v = acc[i][j][r] + bb;
          if (z == 0) v *= 1.44269504f;  // Q *= log2(e)
          const short hv = f2bf(v);
          if (z == 1)
            Ko[(size_t)((b * H_ + h) * S_ + s) * DK_ + dk] = hv;
          else
            Qo[(size_t)((b * H_ + h) * S_ + s) * DK_ + dk] = hv;
        }
      }
    }
  }
}

// Output projection: out = AO(bf16) @ Wo + bo, f32 row-major.
__global__ __launch_bounds__(256) void gemm_out(
    const short* __restrict__ AO, const short* __restrict__ Wot,
    const float* __restrict__ bo, float* __restrict__ out) {
  __shared__ __align__(16) short As[2 * 4096];
  __shared__ __align__(16) short Bs[2 * 4096];
  const int tm = blockIdx.x * 128, tn = blockIdx.y * 128;
  f32x4 acc[4][4] = {};
  gemm_core_512(AO, Wot, As, Bs, tm, tn, acc);

  const int tid = threadIdx.x;
  const int wave = tid >> 6, lane = tid & 63;
  const int wm = (wave >> 1) * 64, wn = (wave & 1) * 64;
  const int c = lane & 15, g = lane >> 4;
#pragma unroll
  for (int i = 0; i < 4; ++i) {
#pragma unroll
    for (int j = 0; j < 4; ++j) {
      const int gc = tn + wn + j * 16 + c;
      const float bb = bo[gc];
#pragma unroll
      for (int r = 0; r < 4; ++r) {
        const int gr = tm + wm + i * 16 + g * 4 + r;
        out[(size_t)gr * E_ + gc] = acc[i][j][r] + bb;
      }
    }
  }
}

// ---- flash attention: r11 8-wave structure, 2-TILE barrier windows -------
// 8 waves = 4 q-groups(64q) x 2 key-halves, 256 q/block, grid 16x16 =
// 1 block/CU. One barrier per 128 keys (was 64): window t = {stage(t+4),
// stage(t+5); bar(vmcnt(4)); qk(t); qk(t+1); softpv(t); softpv(t+1)}.
// K/V 6-buffered (96KB LDS): window writes (t+4)%6,(t+5)%6; reads t%6,
// (t+1)%6 (distance 4,5 != 0 mod 6 -> disjoint). Residency leads reads by
// a FULL window (~1200cyc >= L2/HBM tail); each window opens with 16
// independent MFMAs -> dep-chain tails amortized over 2x longer phases.
// Everything else identical to r11: pre-gathered conflict-free fragments,
// tau-permuted K, no-max softmax (Q pre-scaled by log2 e), per-lane l sums,
// end-of-kernel key-half merge via dead-LDS overlay.
__global__ __launch_bounds__(512, 2) void attn_fwd(
    const short* __restrict__ Q, const short* __restrict__ K,
    const short* __restrict__ Vt, short* __restrict__ O) {
  __shared__ __align__(16) char lds[98304];  // K 6x8K | V 6x8K; merge overlay
  const int tid = threadIdx.x;
  const int wave = tid >> 6, lane = tid & 63;
  const int g = wave >> 1, kh = wave & 1;
  const int qi = lane & 31, hi = lane >> 5;
  const int bh = blockIdx.y;
  const int b = bh >> 3, h = bh & 7;
  const int q0 = blockIdx.x * 256 + g * 64;
  const short* Qp = Q + (size_t)bh * S_ * DK_;
  const short* Kp = K + (size_t)bh * S_ * DK_;
  const short* Vp = Vt + (size_t)bh * DK_ * S_;

  s16x8 qfL[4], qfH[4];
#pragma unroll
  for (int s = 0; s < 4; ++s) {
    qfL[s] = *(const s16x8*)(Qp + (size_t)(q0 + qi) * DK_ + s * 16 + hi * 8);
    qfH[s] = *(const s16x8*)(Qp + (size_t)(q0 + 32 + qi) * DK_ + s * 16 + hi * 8);
  }

  f32x16 o00 = {}, o01 = {}, o10 = {}, o11 = {};  // o[dkh][qh]
  float lsL = 0.f, lsH = 0.f;                     // denominator partials

  // per-lane gather offsets: wave stages K frag `wave` and V frag `wave`
  int kOff, vOff;
  {
    const int j = wave;                    // 0..7
    const int row = (j >> 2) * 32 + qi;    // K source row (pre-tau)
    const int srow = (row & 32) | ((row & 8) << 1) | ((row & 4) << 1) |
                     ((row & 16) >> 2) | (row & 3);  // tau permute
    kOff = srow * DK_ + (j & 3) * 16 + hi * 8;
    vOff = ((j >> 2) * 32 + qi) * S_ + ((j >> 1) & 1) * 32 +
           (j & 1) * 16 + hi * 8;
  }

  // stage tile kt: K frags -> lds[(kt%6)*8K], V frags -> lds[48K+(kt%6)*8K]
  auto stage = [&](int kt) {
    gload_lds16(Kp + (size_t)kt * 64 * DK_ + kOff,
                lds + (kt % 6) * 8192 + wave * 1024);
    gload_lds16(Vp + (size_t)kt * 64 + vOff,
                lds + 49152 + (kt % 6) * 8192 + wave * 1024);
  };

  // counted-vmcnt barrier: retires the PREVIOUS window's 4 loads (making
  // tiles t+2,t+3 resident one window before they're read); the 4 just
  // issued stay in flight across the barrier.
  auto bar4 = [&]() {
    asm volatile("s_waitcnt vmcnt(4) lgkmcnt(0)" ::: "memory");
    __builtin_amdgcn_s_barrier();
  };
  auto bar0 = [&]() {
    asm volatile("s_waitcnt vmcnt(0) lgkmcnt(0)" ::: "memory");
    __builtin_amdgcn_s_barrier();
  };

  const int lbK = kh * 4096 + (lane << 4);

  auto qk = [&](int t, f32x16& sL, f32x16& sH) {
    const char* Kc = lds + (t % 6) * 8192 + lbK;
    f32x16 a = {}, c = {};
    __builtin_amdgcn_s_setprio(1);
#pragma unroll
    for (int s = 0; s < 4; ++s) {
      s16x8 ka = *(const s16x8*)(Kc + s * 1024);
      a = mfma3232(ka, qfL[s], a);
      c = mfma3232(ka, qfH[s], c);
    }
    __builtin_amdgcn_s_setprio(0);
    sL = a; sH = c;
  };

  auto softpv = [&](const f32x16& sL, const f32x16& sH, int t) {
    const char* Vc = lds + 49152 + (t % 6) * 8192 + kh * 2048 + (lane << 4);
    float pL[16], pH[16];
#pragma unroll
    for (int r = 0; r < 16; ++r) { pL[r] = fastexp2(sL[r]); pH[r] = fastexp2(sH[r]); }
    float aL = 0.f, aH = 0.f;
#pragma unroll
    for (int r = 0; r < 16; ++r) { aL += pL[r]; aH += pH[r]; }
    lsL += aL; lsH += aH;
    s16x8 pbL[2], pbH[2];
#pragma unroll
    for (int ks = 0; ks < 2; ++ks)
#pragma unroll
      for (int j = 0; j < 8; ++j) {
        const int r = (j & 3) | (ks << 2) | ((j >> 2) << 3);
        pbL[ks][j] = f2bf(pL[r]);
        pbH[ks][j] = f2bf(pH[r]);
      }
    __builtin_amdgcn_s_setprio(1);
#pragma unroll
    for (int ks = 0; ks < 2; ++ks) {
      s16x8 va0 = *(const s16x8*)(Vc + ks * 1024);          // dk 0-31
      s16x8 va1 = *(const s16x8*)(Vc + 4096 + ks * 1024);   // dk 32-63
      o00 = mfma3232(va0, pbL[ks], o00);
      o01 = mfma3232(va0, pbH[ks], o01);
      o10 = mfma3232(va1, pbL[ks], o10);
      o11 = mfma3232(va1, pbH[ks], o11);
    }
    __builtin_amdgcn_s_setprio(0);
  };

  const int NT = S_ / 64;
  f32x16 sA0, sA1, sB0, sB1;

  // prologue: stage 0..3 (8 loads); bar retires 0,1 (2,3 stay in flight)
  stage(0); stage(1); stage(2); stage(3);
  bar4();

  for (int t = 0; t < NT; t += 2) {
    // stage t+4,t+5; bar retires t+2,t+3 (read NEXT window — full-window lead)
    if (t + 4 < NT) { stage(t + 4); stage(t + 5); bar4(); } else bar0();
    qk(t, sA0, sA1);
    qk(t + 1, sB0, sB1);
    softpv(sA0, sA1, t);
    softpv(sB0, sB1, t + 1);
  }

  lsL += __shfl_xor(lsL, 32);
  lsH += __shfl_xor(lsH, 32);

  // ---- key-half merge: plain addition (no-max softmax partials exact) ----
  float* mrg = (float*)lds;
  const int mi = (g * 64 + lane) * 36;
  __syncthreads();
  if (kh) {
#pragma unroll
    for (int r = 0; r < 4; ++r) {
      *(f32x4*)(mrg + mi + r * 4) =
          f32x4{o00[r * 4], o00[r * 4 + 1], o00[r * 4 + 2], o00[r * 4 + 3]};
      *(f32x4*)(mrg + mi + 16 + r * 4) =
          f32x4{o01[r * 4], o01[r * 4 + 1], o01[r * 4 + 2], o01[r * 4 + 3]};
    }
    mrg[mi + 32] = lsL;
    mrg[mi + 33] = lsH;
  }
  __syncthreads();
  float rlL = 0.f, rlH = 0.f;
  if (!kh) {
#pragma unroll
    for (int r = 0; r < 16; ++r) {
      o00[r] += mrg[mi + r];
      o01[r] += mrg[mi + 16 + r];
    }
    rlL = 1.f / (lsL + mrg[mi + 32]);
    rlH = 1.f / (lsH + mrg[mi + 33]);
  }
  __syncthreads();
  if (kh) {
#pragma unroll
    for (int r = 0; r < 4; ++r) {
      *(f32x4*)(mrg + mi + r * 4) =
          f32x4{o10[r * 4], o10[r * 4 + 1], o10[r * 4 + 2], o10[r * 4 + 3]};
      *(f32x4*)(mrg + mi + 16 + r * 4) =
          f32x4{o11[r * 4], o11[r * 4 + 1], o11[r * 4 + 2], o11[r * 4 + 3]};
    }
  }
  __syncthreads();
  if (!kh) {
#pragma unroll
    for (int r = 0; r < 16; ++r) {
      o10[r] += mrg[mi + r];
      o11[r] += mrg[mi + 16 + r];
    }
    short* OpL = O + ((size_t)(b * S_ + q0 + qi)) * E_ + h * DK_;
    short* OpH = O + ((size_t)(b * S_ + q0 + 32 + qi)) * E_ + h * DK_;
#pragma unroll
    for (int rr = 0; rr < 4; ++rr) {
      s16x4 vL0, vL1, vH0, vH1;
#pragma unroll
      for (int e = 0; e < 4; ++e) {
        vL0[e] = f2bf(o00[rr * 4 + e] * rlL);
        vL1[e] = f2bf(o10[rr * 4 + e] * rlL);
        vH0[e] = f2bf(o01[rr * 4 + e] * rlH);
        vH1[e] = f2bf(o11[rr * 4 + e] * rlH);
      }
      *(s16x4*)(OpL + rr * 8 + hi * 4) = vL0;
      *(s16x4*)(OpL + 32 + rr * 8 + hi * 4) = vL1;
      *(s16x4*)(OpH + rr * 8 + hi * 4) = vH0;
      *(s16x4*)(OpH + 32 + rr * 8 + hi * 4) = vH1;
    }
  }
}

// ---------------- launch ----------------
extern "C" void kernel_launch(void* const* d_in, const int* in_sizes, int n_in,
                              void* d_out, int out_size, void* d_ws, size_t ws_size,
                              hipStream_t stream) {
  const float* query  = (const float*)d_in[0];
  const float* key_in = (const float*)d_in[1];
  const float* value  = (const float*)d_in[2];
  const float* Wq = (const float*)d_in[3];
  const float* bq = (const float*)d_in[4];
  const float* Wk = (const float*)d_in[5];
  const float* bk = (const float*)d_in[6];
  const float* Wv = (const float*)d_in[7];
  const float* bv = (const float*)d_in[8];
  const float* Wo = (const float*)d_in[9];
  const float* bo = (const float*)d_in[10];
  float* out = (float*)d_out;

  const size_t NA = (size_t)M_ * E_;  // 4,194,304
  short* ws  = (short*)d_ws;
  short* Wt  = ws;                    // bf16 W^T, q/k/v/o fused [4E][E]
  short* Wot = Wt + 3 * E_ * E_;
  short* Qb  = Wt + 4 * E_ * E_;      // bf16 [B,H,S,DK] (pre-scaled log2e)
  short* Kb  = Qb + NA;               // bf16 [B,H,S,DK]
  short* Vtb = Kb + NA;               // bf16 [B,H,DK,S]
  short* AO  = Vtb + NA;              // bf16 attn out [B,S,E]

  conv_wT_all<<<dim3(E_ * E_ / 256, 4), 256, 0, stream>>>(Wq, Wk, Wv, Wo, Wt);

  gemm_qkv<<<dim3(M_ / 128, E_ / 128, 3), 256, 0, stream>>>(
      query, key_in, value, Wt, bq, bk, bv, Qb, Kb, Vtb);
  attn_fwd<<<dim3(S_ / 256, B_ * H_), 512, 0, stream>>>(Qb, Kb, Vtb, AO);
  gemm_out<<<dim3(M_ / 128, E_ / 128), 256, 0, stream>>>(AO, Wot, bo, out);
}